// Round 14
// baseline (206.742 us; speedup 1.0000x reference)
//
#include <hip/hip_runtime.h>
#include <cstddef>

// Problem dims (fixed by setup_inputs)
constexpr int B  = 128;   // batch
constexpr int T  = 1024;  // time
constexpr int AD = 512;   // annot dim
constexpr int R  = 1024;  // rnn dim
constexpr int M  = 256;   // memory dim
constexpr int DD = 256;   // attn dim
constexpr int F  = 32;    // loc filters
constexpr int KW = 31;    // conv kernel
constexpr int PADW = 15;
constexpr int XDIM = M + AD;  // 768
constexpr int G3 = 3 * R;     // 3072
constexpr size_t BG3 = (size_t)B * G3;

using short8 = __attribute__((ext_vector_type(8))) short;
using f32x4  = __attribute__((ext_vector_type(4))) float;

__device__ __forceinline__ float sigmoidf(float x) { return 1.f / (1.f + __expf(-x)); }

__device__ __forceinline__ unsigned short f2bf(float x) {  // RNE fp32->bf16
  unsigned int u = __float_as_uint(x);
  u += 0x7FFFu + ((u >> 16) & 1u);
  return (unsigned short)(u >> 16);
}

__device__ __forceinline__ float tanh_fast(float x) {
  float e = __expf(2.f * x);
  return 1.f - 2.f / (e + 1.f);
}

__device__ __forceinline__ uint4 pack_bf8(float4 f0, float4 f1) {
  uint4 r;
  r.x = f2bf(f0.x) | ((unsigned)f2bf(f0.y) << 16);
  r.y = f2bf(f0.z) | ((unsigned)f2bf(f0.w) << 16);
  r.z = f2bf(f1.x) | ((unsigned)f2bf(f1.y) << 16);
  r.w = f2bf(f1.z) | ((unsigned)f2bf(f1.w) << 16);
  return r;
}

// ---------------- prep: a_w, loc_w -> plain bf16 ----------------
__global__ __launch_bounds__(256) void prep_bf16(const float* __restrict__ aw,
                                                 const float* __restrict__ lw,
                                                 unsigned short* __restrict__ awb,
                                                 unsigned short* __restrict__ lwb) {
  int idx = blockIdx.x * 256 + threadIdx.x;
  if (idx < DD * AD) {
    awb[idx] = f2bf(aw[idx]);
  } else {
    int j = idx - DD * AD;
    if (j < DD * F) lwb[j] = f2bf(lw[j]);
  }
}

// ---------------- prep: GRU operands -> bf16 (Wi, Wh, x=concat, rnn) ----------------
__global__ __launch_bounds__(256) void prep_gru(const float* __restrict__ mem,
                                                const float* __restrict__ ctxin,
                                                const float* __restrict__ rnn,
                                                const float* __restrict__ Wi,
                                                const float* __restrict__ Wh,
                                                unsigned short* __restrict__ Wib,
                                                unsigned short* __restrict__ Whb,
                                                unsigned short* __restrict__ xb,
                                                unsigned short* __restrict__ rnnb) {
  const int t = blockIdx.x * 256 + threadIdx.x;   // < 716800
  const float* src;
  unsigned short* dst;
  if (t < 294912) {                         // Wi: 3072*768
    src = Wi + (size_t)t * 8;
    dst = Wib + (size_t)t * 8;
  } else if (t < 688128) {                  // Wh: 3072*1024
    size_t e = (size_t)(t - 294912) * 8;
    src = Wh + e;
    dst = Whb + e;
  } else if (t < 700416) {                  // x = concat(mem, ctx): 128*768
    size_t e = (size_t)(t - 688128) * 8;
    int row = (int)(e / XDIM), col = (int)(e % XDIM);
    src = (col < M) ? (mem + (size_t)row * M + col)
                    : (ctxin + (size_t)row * AD + (col - M));
    dst = xb + e;
  } else {                                  // rnn: 128*1024
    size_t e = (size_t)(t - 700416) * 8;
    src = rnn + e;
    dst = rnnb + e;
  }
  float4 f0 = *(const float4*)src;
  float4 f1 = *(const float4*)(src + 4);
  *(uint4*)dst = pack_bf8(f0, f1);
}

// ---------------- location conv -> locw bf16 [B][T][F] ----------------
__global__ __launch_bounds__(256) void loc_conv(const float* __restrict__ atten,
                                                const float* __restrict__ conv_w,
                                                unsigned short* __restrict__ locw) {
  __shared__ float s_att[2 * 94];
  __shared__ float s_cw[F * 62];
  const int tid = threadIdx.x;
  const int t0 = blockIdx.x * 64, b = blockIdx.y;
  for (int i = tid; i < 2 * 94; i += 256) {
    int c = i / 94, ii = i - c * 94;
    int gt = t0 - PADW + ii;
    s_att[i] = (gt >= 0 && gt < T) ? atten[((size_t)b * 2 + c) * T + gt] : 0.f;
  }
  for (int i = tid; i < F * 62; i += 256) s_cw[i] = conv_w[i];
  __syncthreads();
  const int f = tid & 31;
  const int tb = (tid >> 5) * 8;
  float a8[8] = {0.f, 0.f, 0.f, 0.f, 0.f, 0.f, 0.f, 0.f};
#pragma unroll
  for (int c = 0; c < 2; ++c) {
    float win[38];
#pragma unroll
    for (int i = 0; i < 38; ++i) win[i] = s_att[c * 94 + tb + i];
#pragma unroll
    for (int k = 0; k < KW; ++k) {
      float w = s_cw[f * 62 + c * 31 + k];
#pragma unroll
      for (int ti = 0; ti < 8; ++ti) a8[ti] += w * win[ti + k];
    }
  }
#pragma unroll
  for (int ti = 0; ti < 8; ++ti)
    locw[((size_t)b * T + t0 + tb + ti) * F + f] = f2bf(a8[ti]);
}

// ---------------- GRU GEMMs via MFMA, barrier-free per-wave ----------------
__global__ __launch_bounds__(256, 2) void gemm_gru(const unsigned short* __restrict__ xb,
                                                   const unsigned short* __restrict__ rnnb,
                                                   const unsigned short* __restrict__ Wib,
                                                   const unsigned short* __restrict__ Whb,
                                                   float* __restrict__ outp) {
  const int tid = threadIdx.x;
  const int wv = tid >> 6, lane = tid & 63;
  const int lm = lane & 15, lg = lane >> 4;
  const int g0 = blockIdx.x * 64;
  const int z = blockIdx.y;
  const int which = z >> 2, q = z & 3;
  const unsigned short* __restrict__ A = which ? rnnb : xb;
  const unsigned short* __restrict__ W = which ? Whb : Wib;
  const int K = which ? R : XDIM;
  const int Kq = K >> 2;           // 256 or 192
  const int nch = Kq >> 5;         // 8 or 6
  float* __restrict__ C = outp + (size_t)z * BG3;

  const unsigned short* aA = A + (size_t)(wv * 32 + lm) * K + q * Kq + lg * 8;
  const unsigned short* bW = W + (size_t)(g0 + lm) * K + q * Kq + lg * 8;

  f32x4 acc[2][4];
#pragma unroll
  for (int i = 0; i < 2; ++i)
#pragma unroll
    for (int j = 0; j < 4; ++j) acc[i][j] = (f32x4){0.f, 0.f, 0.f, 0.f};

#pragma unroll 2
  for (int ch = 0; ch < nch; ++ch) {
    const int k = ch * 32;
    short8 a8[2], b8[4];
#pragma unroll
    for (int i = 0; i < 2; ++i)
      a8[i] = *(const short8*)(aA + (size_t)i * 16 * K + k);
#pragma unroll
    for (int j = 0; j < 4; ++j)
      b8[j] = *(const short8*)(bW + (size_t)j * 16 * K + k);
#pragma unroll
    for (int j = 0; j < 4; ++j)
#pragma unroll
      for (int i = 0; i < 2; ++i)
        acc[i][j] = __builtin_amdgcn_mfma_f32_16x16x32_bf16(a8[i], b8[j], acc[i][j], 0, 0, 0);
  }

#pragma unroll
  for (int i = 0; i < 2; ++i)
#pragma unroll
    for (int reg = 0; reg < 4; ++reg) {
      const size_t row = (size_t)(wv * 32 + i * 16 + lg * 4 + reg) * G3 + g0 + lm;
#pragma unroll
      for (int j = 0; j < 4; ++j) C[row + j * 16] = acc[i][j][reg];
    }
}

// ---------------- GRU gate combine (sums 8 K-split partials + biases) ----------------
__global__ __launch_bounds__(256) void gru_combine(const float* __restrict__ gp,
                                                   const float* __restrict__ bi,
                                                   const float* __restrict__ bh,
                                                   const float* __restrict__ hprev,
                                                   float* __restrict__ hout) {
  int idx = blockIdx.x * 256 + threadIdx.x;   // < B*R
  int b = idx >> 10, j = idx & (R - 1);
  float ir = bi[j], iz = bi[R + j], inn = bi[2 * R + j];
  float hr = bh[j], hz = bh[R + j], hn = bh[2 * R + j];
#pragma unroll
  for (int z = 0; z < 4; ++z) {
    const float* g = gp + (size_t)z * BG3 + (size_t)b * G3;
    ir += g[j]; iz += g[R + j]; inn += g[2 * R + j];
  }
#pragma unroll
  for (int z = 4; z < 8; ++z) {
    const float* g = gp + (size_t)z * BG3 + (size_t)b * G3;
    hr += g[j]; hz += g[R + j]; hn += g[2 * R + j];
  }
  float r = sigmoidf(ir + hr);
  float z = sigmoidf(iz + hz);
  float n = tanhf(inn + r * hn);
  float hp = hprev[(size_t)b * R + j];
  hout[(size_t)b * R + j] = (1.f - z) * n + z * hp;
}

// ---------------- pq[b][d] = h[b,:] . q_w[d,:] + q_b[d] ----------------
__global__ __launch_bounds__(256) void pq_kernel(const float* __restrict__ h,
                                                 const float* __restrict__ q_w,
                                                 const float* __restrict__ q_b,
                                                 float* __restrict__ pq) {
  __shared__ __align__(16) float sh[R];
  int b = blockIdx.x, tid = threadIdx.x;
  ((float4*)sh)[tid] = ((const float4*)(h + (size_t)b * R))[tid];
  __syncthreads();
  const float* wr = q_w + (size_t)tid * R;
  float acc = 0.f;
#pragma unroll 4
  for (int k = 0; k < R; k += 4) {
    float4 w = *(const float4*)&wr[k];
    float4 x = *(const float4*)&sh[k];
    acc += w.x * x.x + w.y * x.y + w.z * x.z + w.w * x.w;
  }
  pq[(size_t)b * DD + tid] = acc + q_b[tid];
}

// ---------------- fused attn: ZERO-period structure ----------------
// grid (16, B), 256 thr = 4 waves; block tile 64t x 256d; wave wv owns 64t x 64d.
// Phase 1 (barrier-free stream): ALL 17 A-chunks (annots fp32->bf16 + loc) staged
//   into 68 KB LDS by an unrolled copy loop; ONE __syncthreads at the end.
// Phase 2 (barrier-free K-loop): A frags from static LDS, B frags from L2-resident
//   plain bf16 weights, 16 MFMA/chunk. No ds_write/glds/barrier/waitcnt in loop.
// PV reads A from LDS. 2 blocks/CU; co-resident blocks' phases overlap.
__global__ __launch_bounds__(256, 2) void attn_fused(
    const float* __restrict__ annots, const unsigned short* __restrict__ locw,
    const int* __restrict__ mask,
    const unsigned short* __restrict__ awb, const unsigned short* __restrict__ lwb,
    const float* __restrict__ loc_b, const float* __restrict__ a_b,
    const float* __restrict__ v_w, const float* __restrict__ pq,
    float* __restrict__ u_out, float* __restrict__ ctx_part,
    float* __restrict__ S_part) {
  __shared__ __align__(16) unsigned short s_A[17 * 2048];  // 68 KB: all A chunks
  __shared__ float s_sc[256 + 64];                         // e-partials + u

  const int tid = threadIdx.x;
  const int wv = tid >> 6, lane = tid & 63;
  const int lm = lane & 15, lg = lane >> 4;
  const int g = blockIdx.x, b = blockIdx.y;
  const int t0 = g * 64;
  const int ar = tid >> 2, au = tid & 3;          // staging: 64 rows x 4 col-octs
  const int asu = au ^ ((ar >> 1) & 3);
  const int sufb = lg ^ ((lm >> 1) & 3);          // fragment-read swizzle

  // ---- phase 1: streaming prologue (no barriers until the end) ----
  const float* arow = annots + ((size_t)b * T + t0 + ar) * AD + au * 8;
#pragma unroll 4
  for (int ks = 0; ks < 16; ++ks) {
    float4 f0 = *(const float4*)(arow + ks * 32);
    float4 f1 = *(const float4*)(arow + ks * 32 + 4);
    *(uint4*)&s_A[ks * 2048 + ar * 32 + asu * 8] = pack_bf8(f0, f1);
  }
  {
    uint4 lv = *(const uint4*)(locw + ((size_t)b * T + t0 + ar) * F + au * 8);
    *(uint4*)&s_A[16 * 2048 + ar * 32 + asu * 8] = lv;
  }

  // ---- acc init: pq + a_b + loc_b ----
  f32x4 acc[4][4];
#pragma unroll
  for (int j = 0; j < 4; ++j) {
    int d = wv * 64 + j * 16 + lm;
    float base = pq[(size_t)b * DD + d] + a_b[d] + loc_b[d];
    f32x4 bv = {base, base, base, base};
#pragma unroll
    for (int i = 0; i < 4; ++i) acc[i][j] = bv;
  }
  __syncthreads();   // the ONLY pre-epilogue barrier

  // ---- phase 2: barrier-free K-loop (A from LDS, B from L2) ----
  const unsigned short* bW = awb + (size_t)(wv * 64 + lm) * AD + lg * 8;
#pragma unroll 2
  for (int ks = 0; ks < 16; ++ks) {
    short8 afr[4], bfr[4];
#pragma unroll
    for (int i = 0; i < 4; ++i)
      afr[i] = *(const short8*)&s_A[ks * 2048 + (i * 16 + lm) * 32 + sufb * 8];
#pragma unroll
    for (int j = 0; j < 4; ++j)
      bfr[j] = *(const short8*)(bW + (size_t)j * 16 * AD + ks * 32);
#pragma unroll
    for (int j = 0; j < 4; ++j)
#pragma unroll
      for (int i = 0; i < 4; ++i)
        acc[i][j] = __builtin_amdgcn_mfma_f32_16x16x32_bf16(afr[i], bfr[j], acc[i][j], 0, 0, 0);
  }
  {  // loc chunk
    const unsigned short* bWl = lwb + (size_t)(wv * 64 + lm) * F + lg * 8;
    short8 afr[4], bfr[4];
#pragma unroll
    for (int i = 0; i < 4; ++i)
      afr[i] = *(const short8*)&s_A[16 * 2048 + (i * 16 + lm) * 32 + sufb * 8];
#pragma unroll
    for (int j = 0; j < 4; ++j)
      bfr[j] = *(const short8*)(bWl + (size_t)j * 16 * F);
#pragma unroll
    for (int j = 0; j < 4; ++j)
#pragma unroll
      for (int i = 0; i < 4; ++i)
        acc[i][j] = __builtin_amdgcn_mfma_f32_16x16x32_bf16(afr[i], bfr[j], acc[i][j], 0, 0, 0);
  }

  // ---- epilogue: e -> u = exp(e) (masked->0); S partial; PV from LDS ----
  float* s_e = s_sc;           // [4][64]
  float* s_u = s_sc + 256;     // [64]
  float vwv[4];
#pragma unroll
  for (int j = 0; j < 4; ++j) vwv[j] = v_w[wv * 64 + j * 16 + lm];
#pragma unroll
  for (int i = 0; i < 4; ++i) {
#pragma unroll
    for (int reg = 0; reg < 4; ++reg) {
      float p = 0.f;
#pragma unroll
      for (int j = 0; j < 4; ++j) p += vwv[j] * tanh_fast(acc[i][j][reg]);
      p += __shfl_xor(p, 1);
      p += __shfl_xor(p, 2);
      p += __shfl_xor(p, 4);
      p += __shfl_xor(p, 8);
      if (lm == 0) s_e[wv * 64 + i * 16 + lg * 4 + reg] = p;
    }
  }
  __syncthreads();
  if (tid < 64) {   // exactly wave 0
    float e = s_e[tid] + s_e[64 + tid] + s_e[128 + tid] + s_e[192 + tid];
    bool mk = mask[(size_t)b * T + t0 + tid] != 0;
    float u = mk ? __expf(e) : 0.f;   // |e| <= sum|v_w| ~ 5 -> exp safe, max-sub dropped
    u_out[(size_t)b * T + t0 + tid] = u;
    s_u[tid] = u;
    float p = u;
    p += __shfl_xor(p, 1);
    p += __shfl_xor(p, 2);
    p += __shfl_xor(p, 4);
    p += __shfl_xor(p, 8);
    p += __shfl_xor(p, 16);
    p += __shfl_xor(p, 32);
    if (tid == 0) S_part[b * 16 + g] = p;
  }
  __syncthreads();
  // PV: thread owns 2 adjacent a-cols over this block's 64 rows, read from LDS
  {
    const int a0 = tid * 2;
    const int c = a0 >> 5, uu = (a0 & 31) >> 3, ee = a0 & 7;
    const unsigned short* base = s_A + c * 2048;
    float c0 = 0.f, c1 = 0.f;
#pragma unroll 4
    for (int t = 0; t < 64; ++t) {
      int su = uu ^ ((t >> 1) & 3);
      unsigned int v = *(const unsigned int*)&base[t * 32 + su * 8 + ee];
      float w = s_u[t];
      c0 += w * __uint_as_float((v & 0xFFFFu) << 16);
      c1 += w * __uint_as_float(v & 0xFFFF0000u);
    }
    float* dst = ctx_part + (size_t)g * ((size_t)B * AD) + (size_t)b * AD + a0;
    dst[0] = c0;
    dst[1] = c1;
  }
}

// ---------------- finalize: normalize align + reduce ctx partials ----------------
__global__ __launch_bounds__(512) void finalize(const float* __restrict__ S_part,
                                                const float* __restrict__ ctx_part,
                                                float* __restrict__ al,
                                                float* __restrict__ ctxo) {
  int b = blockIdx.x, tid = threadIdx.x;
  float S = 0.f;
#pragma unroll
  for (int g = 0; g < 16; ++g) S += S_part[b * 16 + g];
  float inv = 1.f / S;
  float2* ap = (float2*)(al + (size_t)b * T);
  float2 v = ap[tid];
  v.x *= inv; v.y *= inv;
  ap[tid] = v;
  float c = 0.f;
#pragma unroll
  for (int p = 0; p < 16; ++p)
    c += ctx_part[(size_t)p * ((size_t)B * AD) + (size_t)b * AD + tid];
  ctxo[(size_t)b * AD + tid] = c * inv;
}

extern "C" void kernel_launch(void* const* d_in, const int* in_sizes, int n_in,
                              void* d_out, int out_size, void* d_ws, size_t ws_size,
                              hipStream_t stream) {
  const float* memory = (const float*)d_in[0];
  const float* context = (const float*)d_in[1];
  const float* rnn = (const float*)d_in[2];
  const float* annots = (const float*)d_in[3];
  const float* atten = (const float*)d_in[4];
  const int* mask = (const int*)d_in[5];
  const float* Wi = (const float*)d_in[6];
  const float* Wh = (const float*)d_in[7];
  const float* bi = (const float*)d_in[8];
  const float* bh = (const float*)d_in[9];
  const float* conv_w = (const float*)d_in[10];
  const float* loc_w = (const float*)d_in[11];
  const float* loc_b = (const float*)d_in[12];
  const float* q_w = (const float*)d_in[13];
  const float* q_b = (const float*)d_in[14];
  const float* a_w = (const float*)d_in[15];
  const float* a_b = (const float*)d_in[16];
  const float* v_w = (const float*)d_in[17];

  float* out = (float*)d_out;
  float* out_h = out;                          // B*R
  float* out_ctx = out + (size_t)B * R;        // B*AD
  float* out_al = out_ctx + (size_t)B * AD;    // B*T

  float* ws = (float*)d_ws;
  float* gp_ws = ws;                                     // 8 * B*G3
  float* pq_ws = gp_ws + 8 * BG3;                        // B*DD
  float* S_part = pq_ws + (size_t)B * DD;                // B*16
  float* ctx_part = S_part + (size_t)B * 16;             // 16 * B*AD
  unsigned short* awb = (unsigned short*)(ctx_part + (size_t)16 * B * AD);  // DD*AD
  unsigned short* lwb = awb + (size_t)DD * AD;           // DD*F
  unsigned short* locw = lwb + (size_t)DD * F;           // B*T*F
  unsigned short* Wib = locw + (size_t)B * T * F;        // 3072*768
  unsigned short* Whb = Wib + (size_t)G3 * XDIM;         // 3072*1024
  unsigned short* xb = Whb + (size_t)G3 * R;             // 128*768
  unsigned short* rnnb = xb + (size_t)B * XDIM;          // 128*1024

  prep_bf16<<<(DD * AD + DD * F) / 256, 256, 0, stream>>>(a_w, loc_w, awb, lwb);
  prep_gru<<<2800, 256, 0, stream>>>(memory, context, rnn, Wi, Wh,
                                     Wib, Whb, xb, rnnb);
  loc_conv<<<dim3(T / 64, B), 256, 0, stream>>>(atten, conv_w, locw);
  gemm_gru<<<dim3(48, 8), 256, 0, stream>>>(xb, rnnb, Wib, Whb, gp_ws);
  gru_combine<<<(B * R) / 256, 256, 0, stream>>>(gp_ws, bi, bh, rnn, out_h);
  pq_kernel<<<B, 256, 0, stream>>>(out_h, q_w, q_b, pq_ws);
  attn_fused<<<dim3(16, B), 256, 0, stream>>>(annots, locw, mask, awb, lwb,
                                              loc_b, a_b, v_w, pq_ws,
                                              out_al, ctx_part, S_part);
  finalize<<<B, 512, 0, stream>>>(S_part, ctx_part, out_al, out_ctx);
}

// Round 15
// 180.585 us; speedup vs baseline: 1.1448x; 1.1448x over previous
//
#include <hip/hip_runtime.h>
#include <cstddef>

// Problem dims (fixed by setup_inputs)
constexpr int B  = 128;   // batch
constexpr int T  = 1024;  // time
constexpr int AD = 512;   // annot dim
constexpr int R  = 1024;  // rnn dim
constexpr int M  = 256;   // memory dim
constexpr int DD = 256;   // attn dim
constexpr int F  = 32;    // loc filters
constexpr int KW = 31;    // conv kernel
constexpr int PADW = 15;
constexpr int XDIM = M + AD;  // 768
constexpr int G3 = 3 * R;     // 3072
constexpr size_t BG3 = (size_t)B * G3;

using short8 = __attribute__((ext_vector_type(8))) short;
using f32x4  = __attribute__((ext_vector_type(4))) float;

__device__ __forceinline__ float sigmoidf(float x) { return 1.f / (1.f + __expf(-x)); }

__device__ __forceinline__ unsigned short f2bf(float x) {  // RNE fp32->bf16
  unsigned int u = __float_as_uint(x);
  u += 0x7FFFu + ((u >> 16) & 1u);
  return (unsigned short)(u >> 16);
}

__device__ __forceinline__ float tanh_fast(float x) {
  float e = __expf(2.f * x);
  return 1.f - 2.f / (e + 1.f);
}

__device__ __forceinline__ uint4 pack_bf8(float4 f0, float4 f1) {
  uint4 r;
  r.x = f2bf(f0.x) | ((unsigned)f2bf(f0.y) << 16);
  r.y = f2bf(f0.z) | ((unsigned)f2bf(f0.w) << 16);
  r.z = f2bf(f1.x) | ((unsigned)f2bf(f1.y) << 16);
  r.w = f2bf(f1.z) | ((unsigned)f2bf(f1.w) << 16);
  return r;
}

// direct global->LDS copy, 16 B per lane; LDS dest = wave-uniform base + lane*16
__device__ __forceinline__ void load_lds16(const void* g, void* l) {
  __builtin_amdgcn_global_load_lds(
      (const __attribute__((address_space(1))) unsigned int*)g,
      (__attribute__((address_space(3))) unsigned int*)l, 16, 0, 0);
}

// ---------------- merged prep: GRU operands -> bf16 AND attn weight images ----------------
// blocks [0, 2800): Wi/Wh/x/rnn -> bf16 (8 elems/thread)
// blocks [2800, 2868): a_w/loc_w -> swizzled bf16 chunk images (awsw/lwsw)
__global__ __launch_bounds__(256) void prep_all(const float* __restrict__ mem,
                                                const float* __restrict__ ctxin,
                                                const float* __restrict__ rnn,
                                                const float* __restrict__ Wi,
                                                const float* __restrict__ Wh,
                                                const float* __restrict__ aw,
                                                const float* __restrict__ lw,
                                                unsigned short* __restrict__ Wib,
                                                unsigned short* __restrict__ Whb,
                                                unsigned short* __restrict__ xb,
                                                unsigned short* __restrict__ rnnb,
                                                unsigned short* __restrict__ awsw,
                                                unsigned short* __restrict__ lwsw) {
  if (blockIdx.x >= 2800) {
    int idx = (blockIdx.x - 2800) * 256 + threadIdx.x;   // < 17*1024
    int chunk = idx >> 10;
    int rn = (idx & 1023) >> 2;
    int u = idx & 3;
    int su = u ^ ((rn >> 1) & 3);
    const float* src;
    unsigned short* dst;
    if (chunk < 16) {
      src = aw + (size_t)rn * AD + chunk * 32 + u * 8;
      dst = awsw + chunk * 8192 + rn * 32 + su * 8;
    } else {
      src = lw + (size_t)rn * F + u * 8;
      dst = lwsw + rn * 32 + su * 8;
    }
    float4 f0 = *(const float4*)src;
    float4 f1 = *(const float4*)(src + 4);
    *(uint4*)dst = pack_bf8(f0, f1);
    return;
  }
  const int t = blockIdx.x * 256 + threadIdx.x;   // < 716800
  const float* src;
  unsigned short* dst;
  if (t < 294912) {                         // Wi: 3072*768
    src = Wi + (size_t)t * 8;
    dst = Wib + (size_t)t * 8;
  } else if (t < 688128) {                  // Wh: 3072*1024
    size_t e = (size_t)(t - 294912) * 8;
    src = Wh + e;
    dst = Whb + e;
  } else if (t < 700416) {                  // x = concat(mem, ctx): 128*768
    size_t e = (size_t)(t - 688128) * 8;
    int row = (int)(e / XDIM), col = (int)(e % XDIM);
    src = (col < M) ? (mem + (size_t)row * M + col)
                    : (ctxin + (size_t)row * AD + (col - M));
    dst = xb + e;
  } else {                                  // rnn: 128*1024
    size_t e = (size_t)(t - 700416) * 8;
    src = rnn + e;
    dst = rnnb + e;
  }
  float4 f0 = *(const float4*)src;
  float4 f1 = *(const float4*)(src + 4);
  *(uint4*)dst = pack_bf8(f0, f1);
}

// ---------------- location conv -> locw bf16 [B][T][F] ----------------
__global__ __launch_bounds__(256) void loc_conv(const float* __restrict__ atten,
                                                const float* __restrict__ conv_w,
                                                unsigned short* __restrict__ locw) {
  __shared__ float s_att[2 * 94];
  __shared__ float s_cw[F * 62];
  const int tid = threadIdx.x;
  const int t0 = blockIdx.x * 64, b = blockIdx.y;
  for (int i = tid; i < 2 * 94; i += 256) {
    int c = i / 94, ii = i - c * 94;
    int gt = t0 - PADW + ii;
    s_att[i] = (gt >= 0 && gt < T) ? atten[((size_t)b * 2 + c) * T + gt] : 0.f;
  }
  for (int i = tid; i < F * 62; i += 256) s_cw[i] = conv_w[i];
  __syncthreads();
  const int f = tid & 31;
  const int tb = (tid >> 5) * 8;
  float a8[8] = {0.f, 0.f, 0.f, 0.f, 0.f, 0.f, 0.f, 0.f};
#pragma unroll
  for (int c = 0; c < 2; ++c) {
    float win[38];
#pragma unroll
    for (int i = 0; i < 38; ++i) win[i] = s_att[c * 94 + tb + i];
#pragma unroll
    for (int k = 0; k < KW; ++k) {
      float w = s_cw[f * 62 + c * 31 + k];
#pragma unroll
      for (int ti = 0; ti < 8; ++ti) a8[ti] += w * win[ti + k];
    }
  }
#pragma unroll
  for (int ti = 0; ti < 8; ++ti)
    locw[((size_t)b * T + t0 + tb + ti) * F + f] = f2bf(a8[ti]);
}

// ---------------- GRU GEMMs via MFMA, barrier-free per-wave ----------------
__global__ __launch_bounds__(256, 2) void gemm_gru(const unsigned short* __restrict__ xb,
                                                   const unsigned short* __restrict__ rnnb,
                                                   const unsigned short* __restrict__ Wib,
                                                   const unsigned short* __restrict__ Whb,
                                                   float* __restrict__ outp) {
  const int tid = threadIdx.x;
  const int wv = tid >> 6, lane = tid & 63;
  const int lm = lane & 15, lg = lane >> 4;
  const int g0 = blockIdx.x * 64;
  const int z = blockIdx.y;
  const int which = z >> 2, q = z & 3;
  const unsigned short* __restrict__ A = which ? rnnb : xb;
  const unsigned short* __restrict__ W = which ? Whb : Wib;
  const int K = which ? R : XDIM;
  const int Kq = K >> 2;           // 256 or 192
  const int nch = Kq >> 5;         // 8 or 6
  float* __restrict__ C = outp + (size_t)z * BG3;

  const unsigned short* aA = A + (size_t)(wv * 32 + lm) * K + q * Kq + lg * 8;
  const unsigned short* bW = W + (size_t)(g0 + lm) * K + q * Kq + lg * 8;

  f32x4 acc[2][4];
#pragma unroll
  for (int i = 0; i < 2; ++i)
#pragma unroll
    for (int j = 0; j < 4; ++j) acc[i][j] = (f32x4){0.f, 0.f, 0.f, 0.f};

#pragma unroll 2
  for (int ch = 0; ch < nch; ++ch) {
    const int k = ch * 32;
    short8 a8[2], b8[4];
#pragma unroll
    for (int i = 0; i < 2; ++i)
      a8[i] = *(const short8*)(aA + (size_t)i * 16 * K + k);
#pragma unroll
    for (int j = 0; j < 4; ++j)
      b8[j] = *(const short8*)(bW + (size_t)j * 16 * K + k);
#pragma unroll
    for (int j = 0; j < 4; ++j)
#pragma unroll
      for (int i = 0; i < 2; ++i)
        acc[i][j] = __builtin_amdgcn_mfma_f32_16x16x32_bf16(a8[i], b8[j], acc[i][j], 0, 0, 0);
  }

#pragma unroll
  for (int i = 0; i < 2; ++i)
#pragma unroll
    for (int reg = 0; reg < 4; ++reg) {
      const size_t row = (size_t)(wv * 32 + i * 16 + lg * 4 + reg) * G3 + g0 + lm;
#pragma unroll
      for (int j = 0; j < 4; ++j) C[row + j * 16] = acc[i][j][reg];
    }
}

// ---------------- GRU gate combine (sums 8 K-split partials + biases) ----------------
__global__ __launch_bounds__(256) void gru_combine(const float* __restrict__ gp,
                                                   const float* __restrict__ bi,
                                                   const float* __restrict__ bh,
                                                   const float* __restrict__ hprev,
                                                   float* __restrict__ hout) {
  int idx = blockIdx.x * 256 + threadIdx.x;   // < B*R
  int b = idx >> 10, j = idx & (R - 1);
  float ir = bi[j], iz = bi[R + j], inn = bi[2 * R + j];
  float hr = bh[j], hz = bh[R + j], hn = bh[2 * R + j];
#pragma unroll
  for (int z = 0; z < 4; ++z) {
    const float* g = gp + (size_t)z * BG3 + (size_t)b * G3;
    ir += g[j]; iz += g[R + j]; inn += g[2 * R + j];
  }
#pragma unroll
  for (int z = 4; z < 8; ++z) {
    const float* g = gp + (size_t)z * BG3 + (size_t)b * G3;
    hr += g[j]; hz += g[R + j]; hn += g[2 * R + j];
  }
  float r = sigmoidf(ir + hr);
  float z = sigmoidf(iz + hz);
  float n = tanhf(inn + r * hn);
  float hp = hprev[(size_t)b * R + j];
  hout[(size_t)b * R + j] = (1.f - z) * n + z * hp;
}

// ---------------- pq[b][d] = h[b,:] . q_w[d,:] + q_b[d] ----------------
__global__ __launch_bounds__(256) void pq_kernel(const float* __restrict__ h,
                                                 const float* __restrict__ q_w,
                                                 const float* __restrict__ q_b,
                                                 float* __restrict__ pq) {
  __shared__ __align__(16) float sh[R];
  int b = blockIdx.x, tid = threadIdx.x;
  ((float4*)sh)[tid] = ((const float4*)(h + (size_t)b * R))[tid];
  __syncthreads();
  const float* wr = q_w + (size_t)tid * R;
  float acc = 0.f;
#pragma unroll 4
  for (int k = 0; k < R; k += 4) {
    float4 w = *(const float4*)&wr[k];
    float4 x = *(const float4*)&sh[k];
    acc += w.x * x.x + w.y * x.y + w.z * x.z + w.w * x.w;
  }
  pq[(size_t)b * DD + tid] = acc + q_b[tid];
}

// ---------------- fused attn (r8/r11 config — best measured): energy + exp + PV ----------------
// grid (8, B), 512 thr = 8 waves (2 wr x 4 wc); wave tile 64t x 64d -> acc 4x4.
// Double-buffered A (reg-staged fp32->bf16, 2-deep prefetch) and B (global_load_lds
// from pre-swizzled images). ONE counted-vmcnt barrier per chunk.
__global__ __launch_bounds__(512, 4) void attn_fused(
    const float* __restrict__ annots, const unsigned short* __restrict__ locw,
    const int* __restrict__ mask,
    const unsigned short* __restrict__ awsw, const unsigned short* __restrict__ lwsw,
    const float* __restrict__ loc_b, const float* __restrict__ a_b,
    const float* __restrict__ v_w, const float* __restrict__ pq,
    float* __restrict__ u_out, float* __restrict__ ctx_part,
    float* __restrict__ S_part) {
  __shared__ __align__(16) unsigned short s_A[2][128 * 32];  // 16 KB
  __shared__ __align__(16) unsigned short s_B[2][256 * 32];  // 32 KB

  const int tid = threadIdx.x;
  const int wv = tid >> 6, lane = tid & 63;
  const int lm = lane & 15, lg = lane >> 4;
  const int wr = wv >> 2, wc = wv & 3;
  const int g = blockIdx.x, b = blockIdx.y;
  const int t0 = g * 128;
  const int ar = tid >> 2, au = tid & 3;          // A staging: 128 rows x 4 col-octs
  const int asu = au ^ ((ar >> 1) & 3);
  const int sufb = lg ^ ((lm >> 1) & 3);          // fragment-read swizzle

  const float* arow = annots + ((size_t)b * T + t0 + ar) * AD + au * 8;

  // ---- prologue: A[0]+B[0] staged; A[1] in flight ----
  {
    float4 f0 = *(const float4*)(arow);
    float4 f1 = *(const float4*)(arow + 4);
    load_lds16(awsw + wv * 1024 + lane * 8, &s_B[0][wv * 1024]);
    load_lds16(awsw + wv * 1024 + 512 + lane * 8, &s_B[0][wv * 1024 + 512]);
    *(uint4*)&s_A[0][ar * 32 + asu * 8] = pack_bf8(f0, f1);
  }
  float4 aN0 = *(const float4*)(arow + 32);
  float4 aN1 = *(const float4*)(arow + 36);
  uint4 lvN = {0, 0, 0, 0};

  // ---- acc init: pq + a_b + loc_b ----
  f32x4 acc[4][4];
#pragma unroll
  for (int j = 0; j < 4; ++j) {
    int d = wc * 64 + j * 16 + lm;
    float base = pq[(size_t)b * DD + d] + a_b[d] + loc_b[d];
    f32x4 bv = {base, base, base, base};
#pragma unroll
    for (int i = 0; i < 4; ++i) acc[i][j] = bv;
  }
  __syncthreads();  // full drain once (prologue)

  // ---- main loop: 17 chunks, ONE counted barrier each ----
#pragma unroll 1
  for (int ks = 0; ks <= 16; ++ks) {
    const int cur = ks & 1, nxt = cur ^ 1;
    // 1) stage B[ks+1] direct to LDS (zero VGPR; retired at the counted barrier)
    if (ks + 1 <= 16) {
      const unsigned short* img = (ks + 1 < 16) ? (awsw + (ks + 1) * 8192) : lwsw;
      load_lds16(img + wv * 1024 + lane * 8, &s_B[nxt][wv * 1024]);
      load_lds16(img + wv * 1024 + 512 + lane * 8, &s_B[nxt][wv * 1024 + 512]);
    }
    // 2) issue A[ks+2] (2-deep prefetch; stays in flight across the barrier)
    float4 aN20, aN21;
    uint4 lvN2;
    if (ks + 2 <= 15) {
      aN20 = *(const float4*)(arow + (ks + 2) * 32);
      aN21 = *(const float4*)(arow + (ks + 2) * 32 + 4);
    } else if (ks + 2 == 16) {
      lvN2 = *(const uint4*)(locw + ((size_t)b * T + t0 + ar) * F + au * 8);
    }
    // 3) convert/store A[ks+1] (loaded a full iteration ago)
    if (ks + 1 <= 15) {
      *(uint4*)&s_A[nxt][ar * 32 + asu * 8] = pack_bf8(aN0, aN1);
    } else if (ks + 1 == 16) {
      *(uint4*)&s_A[nxt][ar * 32 + asu * 8] = lvN;
    }
    // 4) fragments from current buffers + MFMA
    short8 afr[4], bfr[4];
#pragma unroll
    for (int i = 0; i < 4; ++i)
      afr[i] = *(const short8*)&s_A[cur][(wr * 64 + i * 16 + lm) * 32 + sufb * 8];
#pragma unroll
    for (int j = 0; j < 4; ++j)
      bfr[j] = *(const short8*)&s_B[cur][(wc * 64 + j * 16 + lm) * 32 + sufb * 8];
#pragma unroll
    for (int j = 0; j < 4; ++j)
#pragma unroll
      for (int i = 0; i < 4; ++i)
        acc[i][j] = __builtin_amdgcn_mfma_f32_16x16x32_bf16(afr[i], bfr[j], acc[i][j], 0, 0, 0);
    // 5) counted barrier: retire B glds + A ds_writes; keep A-prefetch flying.
    if (ks <= 13) {
      asm volatile("s_waitcnt vmcnt(2) lgkmcnt(0)" ::: "memory");
    } else if (ks == 14) {
      asm volatile("s_waitcnt vmcnt(1) lgkmcnt(0)" ::: "memory");
    } else {
      asm volatile("s_waitcnt vmcnt(0) lgkmcnt(0)" ::: "memory");
    }
    __builtin_amdgcn_s_barrier();
    // 6) rotate prefetch registers
    if (ks + 2 <= 15) { aN0 = aN20; aN1 = aN21; }
    else if (ks + 2 == 16) lvN = lvN2;
  }

  // ---- epilogue: e -> u = exp(e) (masked->0); S partial; PV from L2 ----
  float* s_e = (float*)s_A;        // 512 floats
  float* s_u = s_e + 512;          // 128 floats
  float* s_red = s_e + 644;        // 2 floats
  float vwv[4];
#pragma unroll
  for (int j = 0; j < 4; ++j) vwv[j] = v_w[wc * 64 + j * 16 + lm];
#pragma unroll
  for (int i = 0; i < 4; ++i) {
#pragma unroll
    for (int reg = 0; reg < 4; ++reg) {
      float p = 0.f;
#pragma unroll
      for (int j = 0; j < 4; ++j) p += vwv[j] * tanh_fast(acc[i][j][reg]);
      p += __shfl_xor(p, 1);
      p += __shfl_xor(p, 2);
      p += __shfl_xor(p, 4);
      p += __shfl_xor(p, 8);
      if (lm == 0) s_e[wc * 128 + wr * 64 + i * 16 + lg * 4 + reg] = p;
    }
  }
  __syncthreads();
  if (tid < 128) {
    float e = s_e[tid] + s_e[128 + tid] + s_e[256 + tid] + s_e[384 + tid];
    bool mk = mask[(size_t)b * T + t0 + tid] != 0;
    float u = mk ? __expf(e) : 0.f;   // |e| <= sum|v_w| ~ 5 -> exp safe, max-sub dropped
    u_out[(size_t)b * T + t0 + tid] = u;
    s_u[tid] = u;
    float p = u;
    p += __shfl_xor(p, 1);
    p += __shfl_xor(p, 2);
    p += __shfl_xor(p, 4);
    p += __shfl_xor(p, 8);
    p += __shfl_xor(p, 16);
    p += __shfl_xor(p, 32);
    if (lane == 0) s_red[tid >> 6] = p;
  }
  __syncthreads();
  if (tid == 0) S_part[b * 8 + g] = s_red[0] + s_red[1];
  // PV: thread owns column a = tid; annots tile is L2-hot
  {
    const float* ap = annots + ((size_t)b * T + t0) * AD + tid;
    float c0 = 0.f, c1 = 0.f, c2 = 0.f, c3 = 0.f;
#pragma unroll 2
    for (int t = 0; t < 128; t += 4) {
      c0 += s_u[t + 0] * ap[(size_t)(t + 0) * AD];
      c1 += s_u[t + 1] * ap[(size_t)(t + 1) * AD];
      c2 += s_u[t + 2] * ap[(size_t)(t + 2) * AD];
      c3 += s_u[t + 3] * ap[(size_t)(t + 3) * AD];
    }
    ctx_part[(size_t)g * ((size_t)B * AD) + (size_t)b * AD + tid] = (c0 + c1) + (c2 + c3);
  }
}

// ---------------- finalize: normalize align + reduce ctx partials ----------------
__global__ __launch_bounds__(512) void finalize(const float* __restrict__ S_part,
                                                const float* __restrict__ ctx_part,
                                                float* __restrict__ al,
                                                float* __restrict__ ctxo) {
  int b = blockIdx.x, tid = threadIdx.x;
  float S = 0.f;
#pragma unroll
  for (int g = 0; g < 8; ++g) S += S_part[b * 8 + g];
  float inv = 1.f / S;
  float2* ap = (float2*)(al + (size_t)b * T);
  float2 v = ap[tid];
  v.x *= inv; v.y *= inv;
  ap[tid] = v;
  float c = 0.f;
#pragma unroll
  for (int p = 0; p < 8; ++p)
    c += ctx_part[(size_t)p * ((size_t)B * AD) + (size_t)b * AD + tid];
  ctxo[(size_t)b * AD + tid] = c * inv;
}

extern "C" void kernel_launch(void* const* d_in, const int* in_sizes, int n_in,
                              void* d_out, int out_size, void* d_ws, size_t ws_size,
                              hipStream_t stream) {
  const float* memory = (const float*)d_in[0];
  const float* context = (const float*)d_in[1];
  const float* rnn = (const float*)d_in[2];
  const float* annots = (const float*)d_in[3];
  const float* atten = (const float*)d_in[4];
  const int* mask = (const int*)d_in[5];
  const float* Wi = (const float*)d_in[6];
  const float* Wh = (const float*)d_in[7];
  const float* bi = (const float*)d_in[8];
  const float* bh = (const float*)d_in[9];
  const float* conv_w = (const float*)d_in[10];
  const float* loc_w = (const float*)d_in[11];
  const float* loc_b = (const float*)d_in[12];
  const float* q_w = (const float*)d_in[13];
  const float* q_b = (const float*)d_in[14];
  const float* a_w = (const float*)d_in[15];
  const float* a_b = (const float*)d_in[16];
  const float* v_w = (const float*)d_in[17];

  float* out = (float*)d_out;
  float* out_h = out;                          // B*R
  float* out_ctx = out + (size_t)B * R;        // B*AD
  float* out_al = out_ctx + (size_t)B * AD;    // B*T

  float* ws = (float*)d_ws;
  float* gp_ws = ws;                                     // 8 * B*G3
  float* pq_ws = gp_ws + 8 * BG3;                        // B*DD
  float* S_part = pq_ws + (size_t)B * DD;                // B*8
  float* ctx_part = S_part + (size_t)B * 8;              // 8 * B*AD
  unsigned short* awsw = (unsigned short*)(ctx_part + (size_t)8 * B * AD);  // 16*8192
  unsigned short* lwsw = awsw + (size_t)16 * 8192;       // 8192
  unsigned short* locw = lwsw + 8192;                    // B*T*F
  unsigned short* Wib = locw + (size_t)B * T * F;        // 3072*768
  unsigned short* Whb = Wib + (size_t)G3 * XDIM;         // 3072*1024
  unsigned short* xb = Whb + (size_t)G3 * R;             // 128*768
  unsigned short* rnnb = xb + (size_t)B * XDIM;          // 128*1024

  prep_all<<<2868, 256, 0, stream>>>(memory, context, rnn, Wi, Wh, a_w, loc_w,
                                     Wib, Whb, xb, rnnb, awsw, lwsw);
  loc_conv<<<dim3(T / 64, B), 256, 0, stream>>>(atten, conv_w, locw);
  gemm_gru<<<dim3(48, 8), 256, 0, stream>>>(xb, rnnb, Wib, Whb, gp_ws);
  gru_combine<<<(B * R) / 256, 256, 0, stream>>>(gp_ws, bi, bh, rnn, out_h);
  pq_kernel<<<B, 256, 0, stream>>>(out_h, q_w, q_b, pq_ws);
  attn_fused<<<dim3(8, B), 512, 0, stream>>>(annots, locw, mask, awsw, lwsw,
                                             loc_b, a_b, v_w, pq_ws,
                                             out_al, ctx_part, S_part);
  finalize<<<B, 512, 0, stream>>>(S_part, ctx_part, out_al, out_ctx);
}